// Round 2
// baseline (4953.957 us; speedup 1.0000x reference)
//
#include <hip/hip_runtime.h>
#include <hip/hip_bf16.h>

#define SEQ   512
#define BATCH 128
#define XD    256
#define PHID  512
#define RD    256
#define OUTD  256
#define NBLK  48
#define RING  8

typedef __attribute__((ext_vector_type(8))) short short8;
typedef __attribute__((ext_vector_type(4))) float floatx4;

#define MFMA(a, b, c) __builtin_amdgcn_mfma_f32_16x16x32_bf16((a), (b), (c), 0, 0, 0)

// counted vmem wait + scheduler pin (guide rule #18)
#define WAITVM(N) do { asm volatile("s_waitcnt vmcnt(" #N ")" ::: "memory"); \
                       __builtin_amdgcn_sched_barrier(0); } while (0)

// bounded spin: converts a protocol bug from a container-wedging hang into a
// verification mismatch (~1 ms cap per wait point)
#define SPIN(cond) do { int _sp = 0; \
    while (cond) { __builtin_amdgcn_s_sleep(1); if (++_sp > (1 << 12)) break; } } while (0)

__device__ inline short8 ldg8(const __hip_bfloat16* p) {
    return *reinterpret_cast<const short8*>(p);
}
// agent-coherent 16B load: sc1 bypasses (possibly stale) per-XCD L2, reads at LLC
__device__ inline void ldcc(short8& d, const __hip_bfloat16* p) {
    asm volatile("global_load_dwordx4 %0, %1, off sc1"
                 : "=v"(d) : "v"(p) : "memory");
}
// agent-coherent 2B store: write-through to LLC (never dirties L2 → release wbl2 is free)
__device__ inline void stcc16(__hip_bfloat16* p, __hip_bfloat16 v) {
    const short sv = __builtin_bit_cast(short, v);
    asm volatile("global_store_short %0, %1, off sc1"
                 :: "v"(p), "v"(sv) : "memory");
}
__device__ inline int flagld(const int* p) {
    return __hip_atomic_load(p, __ATOMIC_RELAXED, __HIP_MEMORY_SCOPE_AGENT);
}
__device__ inline void flagst(int* p, int v) {
    __hip_atomic_store(p, v, __ATOMIC_RELAXED, __HIP_MEMORY_SCOPE_AGENT);
}
__device__ inline void flagst_rel(int* p, int v) {
    __hip_atomic_store(p, v, __ATOMIC_RELEASE, __HIP_MEMORY_SCOPE_AGENT);
}

__global__ void convert_x(const float* __restrict__ x, __hip_bfloat16* __restrict__ xbf) {
    const int gid = blockIdx.x * blockDim.x + threadIdx.x;   // grid covers N/4 exactly
    const float4 v = reinterpret_cast<const float4*>(x)[gid];
    __hip_bfloat16* d = xbf + 4 * (size_t)gid;
    d[0] = __float2bfloat16(v.x); d[1] = __float2bfloat16(v.y);
    d[2] = __float2bfloat16(v.z); d[3] = __float2bfloat16(v.w);
}

// 48 persistent blocks:
//   bid  0..15 : phi-blocks  — 32 cols of phi each; x-part GEMM overlaps the r-wait
//   bid 16..31 : s-blocks    — 16 cols of r; keep s_a = mu_a @ W1_a^T in regs (4 alphas)
//   bid 32..47 : o-blocks    — 16 cols of out; keep o_a = mu_a @ Wo_a^T in regs (lag freely)
// Protocol (fence-light): all cross-block data moves via sc1 (agent-coherent) accesses.
//   producer: sc1 write-through stores -> s_waitcnt vmcnt(0) -> __syncthreads -> RELEASE flag
//   consumer: relaxed spin on flag -> __syncthreads -> sc1 loads (no stale L2 lines possible)
__global__ void __launch_bounds__(256) sru_pipe(
    const float* __restrict__ W1, const float* __restrict__ W2,
    const float* __restrict__ Wo,
    const float* __restrict__ b1, const float* __restrict__ b2,
    const float* __restrict__ bo,
    const __hip_bfloat16* __restrict__ xbf,
    __hip_bfloat16* __restrict__ rbf,
    __hip_bfloat16* __restrict__ phib,
    float* __restrict__ out, int* __restrict__ ctrl)
{
    __shared__ __hip_bfloat16 wlds[32768];   // 64 KB
    const int bid  = blockIdx.x;
    const int tid  = threadIdx.x;
    const int wave = tid >> 6;
    const int lane = tid & 63;
    const int quad = lane >> 4;
    const int lrow = lane & 15;
    const int m0   = wave * 32;              // each wave owns 32 batch rows
    int* rfl = ctrl;
    int* pfl = ctrl + 256;
    int* ofl = ctrl + 512;

    if (bid < 16) {
        // ================= phi-block =================
        const int j0 = bid * 32;
        for (int i = tid * 4; i < 2 * 32 * 256; i += 1024) {
            const int part = i >> 13, rem = i & 8191;
            const int n = rem >> 8, k = rem & 255;
            const float4 v = *reinterpret_cast<const float4*>(
                &W2[(j0 + n) * (XD + RD) + part * 256 + k]);
            __hip_bfloat16* dst = &wlds[(((part * 32 + (k >> 3)) * 32 + n) << 3) + (k & 7)];
            dst[0] = __float2bfloat16(v.x); dst[1] = __float2bfloat16(v.y);
            dst[2] = __float2bfloat16(v.z); dst[3] = __float2bfloat16(v.w);
        }
        __syncthreads();
        const float bj0 = b2[j0 + lrow];
        const float bj1 = b2[j0 + 16 + lrow];
        const __hip_bfloat16* rb0 = rbf + (m0 + lrow) * RD + 8 * quad;
        const __hip_bfloat16* rb1 = rbf + (m0 + 16 + lrow) * RD + 8 * quad;
        #pragma unroll 1
        for (int t = 0; t < SEQ; ++t) {
            floatx4 acc[2][2] = {};
            // x-part (no dependency on this step's r) — overlaps the r-wait below
            const __hip_bfloat16* xt = xbf + (size_t)(t * BATCH + m0) * XD;
            #pragma unroll
            for (int k = 0; k < XD; k += 32) {
                const short8 a0 = ldg8(xt + lrow * XD + k + 8 * quad);
                const short8 a1 = ldg8(xt + (16 + lrow) * XD + k + 8 * quad);
                #pragma unroll
                for (int j2 = 0; j2 < 2; ++j2) {
                    const short8 b = *reinterpret_cast<const short8*>(
                        &wlds[((((k >> 3) + quad) * 32 + j2 * 16 + lrow) << 3)]);
                    acc[0][j2] = MFMA(a0, b, acc[0][j2]);
                    acc[1][j2] = MFMA(a1, b, acc[1][j2]);
                }
            }
            // wait r_t (16 s-flags); gate phi ring slot on o-progress (ring of 8 -> t-7)
            if (tid < 16) {
                SPIN(flagld(&rfl[tid * 16]) < t + 1);
            } else if (tid < 32) {
                const int g = t - 7;
                SPIN(flagld(&ofl[(tid - 16) * 16]) < g);
            }
            __syncthreads();
            // r-part: agent-coherent loads, double-buffered counted-vmcnt batches
            short8 ra[2][4][2];
            #pragma unroll
            for (int ki = 0; ki < 4; ++ki) {
                ldcc(ra[0][ki][0], rb0 + ki * 32);
                ldcc(ra[0][ki][1], rb1 + ki * 32);
            }
            #pragma unroll
            for (int g = 0; g < 2; ++g) {
                if (g == 0) {
                    #pragma unroll
                    for (int ki = 0; ki < 4; ++ki) {
                        ldcc(ra[1][ki][0], rb0 + 128 + ki * 32);
                        ldcc(ra[1][ki][1], rb1 + 128 + ki * 32);
                    }
                    WAITVM(8);
                } else {
                    WAITVM(0);
                }
                #pragma unroll
                for (int ki = 0; ki < 4; ++ki) {
                    const int k = g * 128 + ki * 32;
                    #pragma unroll
                    for (int j2 = 0; j2 < 2; ++j2) {
                        const short8 b = *reinterpret_cast<const short8*>(
                            &wlds[(((32 + (k >> 3) + quad) * 32 + j2 * 16 + lrow) << 3)]);
                        acc[0][j2] = MFMA(ra[g][ki][0], b, acc[0][j2]);
                        acc[1][j2] = MFMA(ra[g][ki][1], b, acc[1][j2]);
                    }
                }
            }
            __hip_bfloat16* pb = phib + (size_t)(t & (RING - 1)) * BATCH * PHID;
            #pragma unroll
            for (int h = 0; h < 2; ++h)
                #pragma unroll
                for (int j2 = 0; j2 < 2; ++j2)
                    #pragma unroll
                    for (int i = 0; i < 4; ++i) {
                        const int row = m0 + 16 * h + quad * 4 + i;
                        const float v = acc[h][j2][i] + (j2 ? bj1 : bj0);
                        stcc16(pb + row * PHID + j0 + j2 * 16 + lrow,
                               __float2bfloat16(fmaxf(v, 0.f)));
                    }
            asm volatile("s_waitcnt vmcnt(0)" ::: "memory");   // stores at LLC
            __syncthreads();
            if (tid == 0) flagst_rel(&pfl[bid * 16], t + 1);
        }
    } else if (bid < 32) {
        // ================= s-block =================
        const int sb = bid - 16, j0 = sb * 16;
        for (int i = tid * 4; i < 4 * 16 * 512; i += 1024) {
            const int a = i >> 13, rem = i & 8191;
            const int n = rem >> 9, k = rem & 511;
            const float4 v = *reinterpret_cast<const float4*>(
                &W1[(j0 + n) * 2048 + a * 512 + k]);
            __hip_bfloat16* dst = &wlds[(((a * 64 + (k >> 3)) * 16 + n) << 3) + (k & 7)];
            dst[0] = __float2bfloat16(v.x); dst[1] = __float2bfloat16(v.y);
            dst[2] = __float2bfloat16(v.z); dst[3] = __float2bfloat16(v.w);
        }
        __syncthreads();
        const float bjv = b1[j0 + lrow];
        const float pre[4]  = {0.f, 1.f, 9.f, 99.f};    // alpha/(1-alpha)
        const float post[4] = {1.f, 0.5f, 0.1f, 0.01f}; // (1-alpha)
        floatx4 s[4][2] = {};
        #pragma unroll 1
        for (int t = 0; t < SEQ; ++t) {
            // emit r_t = relu(sum_a s_a + b1), agent-coherent write-through
            #pragma unroll
            for (int h = 0; h < 2; ++h)
                #pragma unroll
                for (int i = 0; i < 4; ++i) {
                    const int row = m0 + 16 * h + quad * 4 + i;
                    const float rv = s[0][h][i] + s[1][h][i] + s[2][h][i] + s[3][h][i] + bjv;
                    stcc16(rbf + row * RD + j0 + lrow, __float2bfloat16(fmaxf(rv, 0.f)));
                }
            asm volatile("s_waitcnt vmcnt(0)" ::: "memory");
            __syncthreads();
            if (tid == 0) flagst_rel(&rfl[sb * 16], t + 1);
            if (t == SEQ - 1) break;
            // wait phi_t
            if (tid < 16) {
                SPIN(flagld(&pfl[tid * 16]) < t + 1);
            }
            __syncthreads();
            #pragma unroll
            for (int a = 0; a < 4; ++a)
                #pragma unroll
                for (int h = 0; h < 2; ++h)
                    s[a][h] *= pre[a];
            const __hip_bfloat16* pb = phib + (size_t)(t & (RING - 1)) * BATCH * PHID;
            const __hip_bfloat16* pb0 = pb + (m0 + lrow) * PHID + 8 * quad;
            const __hip_bfloat16* pb1 = pb + (m0 + 16 + lrow) * PHID + 8 * quad;
            short8 fa[2][4][2];
            #pragma unroll
            for (int ki = 0; ki < 4; ++ki) {
                ldcc(fa[0][ki][0], pb0 + ki * 32);
                ldcc(fa[0][ki][1], pb1 + ki * 32);
            }
            #pragma unroll
            for (int g = 0; g < 4; ++g) {
                if (g < 3) {
                    #pragma unroll
                    for (int ki = 0; ki < 4; ++ki) {
                        ldcc(fa[(g + 1) & 1][ki][0], pb0 + (g + 1) * 128 + ki * 32);
                        ldcc(fa[(g + 1) & 1][ki][1], pb1 + (g + 1) * 128 + ki * 32);
                    }
                    WAITVM(8);
                } else {
                    WAITVM(0);
                }
                #pragma unroll
                for (int ki = 0; ki < 4; ++ki) {
                    const int k = g * 128 + ki * 32;
                    #pragma unroll
                    for (int a = 0; a < 4; ++a) {
                        const short8 b = *reinterpret_cast<const short8*>(
                            &wlds[(((a * 64 + (k >> 3) + quad) * 16 + lrow) << 3)]);
                        s[a][0] = MFMA(fa[g & 1][ki][0], b, s[a][0]);
                        s[a][1] = MFMA(fa[g & 1][ki][1], b, s[a][1]);
                    }
                }
            }
            #pragma unroll
            for (int a = 0; a < 4; ++a)
                #pragma unroll
                for (int h = 0; h < 2; ++h)
                    s[a][h] *= post[a];
        }
    } else {
        // ================= o-block =================
        const int ob = bid - 32, j0 = ob * 16;
        for (int i = tid * 4; i < 4 * 16 * 512; i += 1024) {
            const int a = i >> 13, rem = i & 8191;
            const int n = rem >> 9, k = rem & 511;
            const float4 v = *reinterpret_cast<const float4*>(
                &Wo[(j0 + n) * 2048 + a * 512 + k]);
            __hip_bfloat16* dst = &wlds[(((a * 64 + (k >> 3)) * 16 + n) << 3) + (k & 7)];
            dst[0] = __float2bfloat16(v.x); dst[1] = __float2bfloat16(v.y);
            dst[2] = __float2bfloat16(v.z); dst[3] = __float2bfloat16(v.w);
        }
        __syncthreads();
        const float pre[4]  = {0.f, 1.f, 9.f, 99.f};
        const float post[4] = {1.f, 0.5f, 0.1f, 0.01f};
        floatx4 o[4][2] = {};
        #pragma unroll 1
        for (int t = 0; t < SEQ; ++t) {
            if (tid < 16) {
                SPIN(flagld(&pfl[tid * 16]) < t + 1);
            }
            __syncthreads();
            #pragma unroll
            for (int a = 0; a < 4; ++a)
                #pragma unroll
                for (int h = 0; h < 2; ++h)
                    o[a][h] *= pre[a];
            const __hip_bfloat16* pb = phib + (size_t)(t & (RING - 1)) * BATCH * PHID;
            const __hip_bfloat16* pb0 = pb + (m0 + lrow) * PHID + 8 * quad;
            const __hip_bfloat16* pb1 = pb + (m0 + 16 + lrow) * PHID + 8 * quad;
            short8 fa[2][4][2];
            #pragma unroll
            for (int ki = 0; ki < 4; ++ki) {
                ldcc(fa[0][ki][0], pb0 + ki * 32);
                ldcc(fa[0][ki][1], pb1 + ki * 32);
            }
            #pragma unroll
            for (int g = 0; g < 4; ++g) {
                if (g < 3) {
                    #pragma unroll
                    for (int ki = 0; ki < 4; ++ki) {
                        ldcc(fa[(g + 1) & 1][ki][0], pb0 + (g + 1) * 128 + ki * 32);
                        ldcc(fa[(g + 1) & 1][ki][1], pb1 + (g + 1) * 128 + ki * 32);
                    }
                    WAITVM(8);
                } else {
                    WAITVM(0);
                }
                #pragma unroll
                for (int ki = 0; ki < 4; ++ki) {
                    const int k = g * 128 + ki * 32;
                    #pragma unroll
                    for (int a = 0; a < 4; ++a) {
                        const short8 b = *reinterpret_cast<const short8*>(
                            &wlds[(((a * 64 + (k >> 3) + quad) * 16 + lrow) << 3)]);
                        o[a][0] = MFMA(fa[g & 1][ki][0], b, o[a][0]);
                        o[a][1] = MFMA(fa[g & 1][ki][1], b, o[a][1]);
                    }
                }
            }
            #pragma unroll
            for (int a = 0; a < 4; ++a)
                #pragma unroll
                for (int h = 0; h < 2; ++h)
                    o[a][h] *= post[a];
            __syncthreads();                  // all waves' phi loads complete (WAITVM(0) above)
            if (tid == 0) flagst(&ofl[ob * 16], t + 1);
        }
        const float bjo = bo[j0 + lrow];
        #pragma unroll
        for (int h = 0; h < 2; ++h)
            #pragma unroll
            for (int i = 0; i < 4; ++i) {
                const int row = m0 + 16 * h + quad * 4 + i;
                const float v = o[0][h][i] + o[1][h][i] + o[2][h][i] + o[3][h][i] + bjo;
                out[row * OUTD + j0 + lrow] = fmaxf(v, 0.f);
            }
    }
}

extern "C" void kernel_launch(void* const* d_in, const int* in_sizes, int n_in,
                              void* d_out, int out_size, void* d_ws, size_t ws_size,
                              hipStream_t stream)
{
    const float* x  = (const float*)d_in[0];
    const float* W1 = (const float*)d_in[1];
    const float* b1 = (const float*)d_in[2];
    const float* W2 = (const float*)d_in[3];
    const float* b2 = (const float*)d_in[4];
    const float* Wo = (const float*)d_in[5];
    const float* bo = (const float*)d_in[6];
    float* out = (float*)d_out;
    char* ws = (char*)d_ws;

    constexpr size_t O_CTRL = 0;                                  // 768 ints, 64B-spaced flags
    constexpr size_t O_RBF  = 4096;                               // 128x256 bf16 = 64 KB
    constexpr size_t O_PHI  = O_RBF + (size_t)BATCH * RD * 2;     // 8 x 128x512 bf16 = 1 MB
    constexpr size_t O_X    = O_PHI + (size_t)RING * BATCH * PHID * 2;  // 32 MB

    hipMemsetAsync(ws + O_CTRL, 0, 3072, stream);
    convert_x<<<SEQ * BATCH * XD / 4 / 256, 256, 0, stream>>>(
        x, (__hip_bfloat16*)(ws + O_X));
    sru_pipe<<<NBLK, 256, 0, stream>>>(
        W1, W2, Wo, b1, b2, bo,
        (const __hip_bfloat16*)(ws + O_X),
        (__hip_bfloat16*)(ws + O_RBF),
        (__hip_bfloat16*)(ws + O_PHI),
        out, (int*)(ws + O_CTRL));
}

// Round 4
// 4853.959 us; speedup vs baseline: 1.0206x; 1.0206x over previous
//
#include <hip/hip_runtime.h>
#include <hip/hip_bf16.h>

#define SEQ   512
#define BATCH 128
#define XD    256
#define PHID  512
#define RD    256
#define OUTD  256
#define NBLK  48
#define RING  16

typedef __attribute__((ext_vector_type(8))) short short8;
typedef __attribute__((ext_vector_type(4))) float floatx4;

#define MFMA(a, b, c) __builtin_amdgcn_mfma_f32_16x16x32_bf16((a), (b), (c), 0, 0, 0)

// counted vmem wait + scheduler pin (guide rule #18)
#define WAITVM(N) do { asm volatile("s_waitcnt vmcnt(" #N ")" ::: "memory"); \
                       __builtin_amdgcn_sched_barrier(0); } while (0)

// tight bounded spin (no sleep): detect latency = one LLC round-trip.
// Cap converts a protocol bug into a fast verification mismatch, not a hang.
#define SPIN(P, TGT) do { int _it = 0; \
    while (flagld(P) < (TGT)) { if (++_it > 32768) break; } } while (0)

__device__ inline short8 ldg8(const __hip_bfloat16* p) {
    return *reinterpret_cast<const short8*>(p);
}
// agent-coherent 16B load: sc1 bypasses (possibly stale) per-XCD L2, reads at LLC
__device__ inline void ldcc(short8& d, const __hip_bfloat16* p) {
    asm volatile("global_load_dwordx4 %0, %1, off sc1"
                 : "=v"(d) : "v"(p) : "memory");
}
// agent-coherent 2B store: write-through to LLC (never dirties L2)
__device__ inline void stcc16(__hip_bfloat16* p, __hip_bfloat16 v) {
    const short sv = __builtin_bit_cast(short, v);
    asm volatile("global_store_short %0, %1, off sc1"
                 :: "v"(p), "v"(sv) : "memory");
}
__device__ inline int flagld(const int* p) {
    return __hip_atomic_load(p, __ATOMIC_RELAXED, __HIP_MEMORY_SCOPE_AGENT);
}
// flag post WITHOUT the release-fence L2 writeback: data stores are sc1
// write-through and already drained (vmcnt(0) before the barrier), so a plain
// sc1 store of the flag preserves the validated ordering at the LLC.
__device__ inline void flag_sc1(int* p, int v) {
    asm volatile("global_store_dword %0, %1, off sc1"
                 :: "v"(p), "v"(v) : "memory");
}

__global__ void convert_x(const float* __restrict__ x, __hip_bfloat16* __restrict__ xbf) {
    const int gid = blockIdx.x * blockDim.x + threadIdx.x;   // grid covers N/4 exactly
    const float4 v = reinterpret_cast<const float4*>(x)[gid];
    __hip_bfloat16* d = xbf + 4 * (size_t)gid;
    d[0] = __float2bfloat16(v.x); d[1] = __float2bfloat16(v.y);
    d[2] = __float2bfloat16(v.z); d[3] = __float2bfloat16(v.w);
}

// 48 persistent blocks:
//   bid  0..15 : phi-blocks  — 32 cols of phi each; x-part GEMM overlaps the r-wait
//   bid 16..31 : s-blocks    — 16 cols of r; keep s_a = mu_a @ W1_a^T in regs (4 alphas)
//   bid 32..47 : o-blocks    — 16 cols of out; keep o_a = mu_a @ Wo_a^T in regs (lag freely)
// Protocol: all cross-block data via sc1 (LLC-coherent) accesses.
//   producer: sc1 write-through stores -> s_waitcnt vmcnt(0) -> __syncthreads -> sc1 flag
//   consumer: tight spin on flag -> __syncthreads -> sc1 loads
__global__ void __launch_bounds__(256) sru_pipe(
    const float* __restrict__ W1, const float* __restrict__ W2,
    const float* __restrict__ Wo,
    const float* __restrict__ b1, const float* __restrict__ b2,
    const float* __restrict__ bo,
    const __hip_bfloat16* __restrict__ xbf,
    __hip_bfloat16* __restrict__ rbf,
    __hip_bfloat16* __restrict__ phib,
    float* __restrict__ out, int* __restrict__ ctrl)
{
    __shared__ __hip_bfloat16 wlds[32768];   // 64 KB
    const int bid  = blockIdx.x;
    const int tid  = threadIdx.x;
    const int wave = tid >> 6;
    const int lane = tid & 63;
    const int quad = lane >> 4;
    const int lrow = lane & 15;
    const int m0   = wave * 32;              // each wave owns 32 batch rows
    int* rfl = ctrl;
    int* pfl = ctrl + 256;
    int* ofl = ctrl + 512;

    if (bid < 16) {
        // ================= phi-block =================
        const int j0 = bid * 32;
        for (int i = tid * 4; i < 2 * 32 * 256; i += 1024) {
            const int part = i >> 13, rem = i & 8191;
            const int n = rem >> 8, k = rem & 255;
            const float4 v = *reinterpret_cast<const float4*>(
                &W2[(j0 + n) * (XD + RD) + part * 256 + k]);
            __hip_bfloat16* dst = &wlds[(((part * 32 + (k >> 3)) * 32 + n) << 3) + (k & 7)];
            dst[0] = __float2bfloat16(v.x); dst[1] = __float2bfloat16(v.y);
            dst[2] = __float2bfloat16(v.z); dst[3] = __float2bfloat16(v.w);
        }
        __syncthreads();
        const float bj0 = b2[j0 + lrow];
        const float bj1 = b2[j0 + 16 + lrow];
        const __hip_bfloat16* rb0 = rbf + (m0 + lrow) * RD + 8 * quad;
        const __hip_bfloat16* rb1 = rbf + (m0 + 16 + lrow) * RD + 8 * quad;
        #pragma unroll 1
        for (int t = 0; t < SEQ; ++t) {
            floatx4 acc[2][2] = {};
            // x-part (no dependency on this step's r) — overlaps the r-wait below
            const __hip_bfloat16* xt = xbf + (size_t)(t * BATCH + m0) * XD;
            #pragma unroll
            for (int k = 0; k < XD; k += 32) {
                const short8 a0 = ldg8(xt + lrow * XD + k + 8 * quad);
                const short8 a1 = ldg8(xt + (16 + lrow) * XD + k + 8 * quad);
                #pragma unroll
                for (int j2 = 0; j2 < 2; ++j2) {
                    const short8 b = *reinterpret_cast<const short8*>(
                        &wlds[((((k >> 3) + quad) * 32 + j2 * 16 + lrow) << 3)]);
                    acc[0][j2] = MFMA(a0, b, acc[0][j2]);
                    acc[1][j2] = MFMA(a1, b, acc[1][j2]);
                }
            }
            // wait r_t (16 s-flags); gate phi ring slot on o-progress (ring 16 -> t-15)
            if (tid < 16) {
                SPIN(&rfl[tid * 16], t + 1);
            } else if (tid < 32) {
                SPIN(&ofl[(tid - 16) * 16], t - 15);
            }
            __syncthreads();
            // r-part: LLC loads, double-buffered counted-vmcnt batches
            short8 ra[2][4][2];
            #pragma unroll
            for (int ki = 0; ki < 4; ++ki) {
                ldcc(ra[0][ki][0], rb0 + ki * 32);
                ldcc(ra[0][ki][1], rb1 + ki * 32);
            }
            #pragma unroll
            for (int g = 0; g < 2; ++g) {
                if (g == 0) {
                    #pragma unroll
                    for (int ki = 0; ki < 4; ++ki) {
                        ldcc(ra[1][ki][0], rb0 + 128 + ki * 32);
                        ldcc(ra[1][ki][1], rb1 + 128 + ki * 32);
                    }
                    WAITVM(8);
                } else {
                    WAITVM(0);
                }
                #pragma unroll
                for (int ki = 0; ki < 4; ++ki) {
                    const int k = g * 128 + ki * 32;
                    #pragma unroll
                    for (int j2 = 0; j2 < 2; ++j2) {
                        const short8 b = *reinterpret_cast<const short8*>(
                            &wlds[(((32 + (k >> 3) + quad) * 32 + j2 * 16 + lrow) << 3)]);
                        acc[0][j2] = MFMA(ra[g][ki][0], b, acc[0][j2]);
                        acc[1][j2] = MFMA(ra[g][ki][1], b, acc[1][j2]);
                    }
                }
            }
            __hip_bfloat16* pb = phib + (size_t)(t & (RING - 1)) * BATCH * PHID;
            #pragma unroll
            for (int h = 0; h < 2; ++h)
                #pragma unroll
                for (int j2 = 0; j2 < 2; ++j2)
                    #pragma unroll
                    for (int i = 0; i < 4; ++i) {
                        const int row = m0 + 16 * h + quad * 4 + i;
                        const float v = acc[h][j2][i] + (j2 ? bj1 : bj0);
                        stcc16(pb + row * PHID + j0 + j2 * 16 + lrow,
                               __float2bfloat16(fmaxf(v, 0.f)));
                    }
            asm volatile("s_waitcnt vmcnt(0)" ::: "memory");   // stores at LLC
            __syncthreads();
            if (tid == 0) flag_sc1(&pfl[bid * 16], t + 1);
        }
    } else if (bid < 32) {
        // ================= s-block =================
        const int sb = bid - 16, j0 = sb * 16;
        for (int i = tid * 4; i < 4 * 16 * 512; i += 1024) {
            const int a = i >> 13, rem = i & 8191;
            const int n = rem >> 9, k = rem & 511;
            const float4 v = *reinterpret_cast<const float4*>(
                &W1[(j0 + n) * 2048 + a * 512 + k]);
            __hip_bfloat16* dst = &wlds[(((a * 64 + (k >> 3)) * 16 + n) << 3) + (k & 7)];
            dst[0] = __float2bfloat16(v.x); dst[1] = __float2bfloat16(v.y);
            dst[2] = __float2bfloat16(v.z); dst[3] = __float2bfloat16(v.w);
        }
        __syncthreads();
        const float bjv = b1[j0 + lrow];
        const float pre[4]  = {0.f, 1.f, 9.f, 99.f};    // alpha/(1-alpha)
        const float post[4] = {1.f, 0.5f, 0.1f, 0.01f}; // (1-alpha)
        floatx4 s[4][2] = {};
        #pragma unroll 1
        for (int t = 0; t < SEQ; ++t) {
            // emit r_t = relu(sum_a s_a + b1), write-through to LLC
            #pragma unroll
            for (int h = 0; h < 2; ++h)
                #pragma unroll
                for (int i = 0; i < 4; ++i) {
                    const int row = m0 + 16 * h + quad * 4 + i;
                    const float rv = s[0][h][i] + s[1][h][i] + s[2][h][i] + s[3][h][i] + bjv;
                    stcc16(rbf + row * RD + j0 + lrow, __float2bfloat16(fmaxf(rv, 0.f)));
                }
            asm volatile("s_waitcnt vmcnt(0)" ::: "memory");
            __syncthreads();
            if (tid == 0) flag_sc1(&rfl[sb * 16], t + 1);
            if (t == SEQ - 1) break;
            // wait phi_t
            if (tid < 16) {
                SPIN(&pfl[tid * 16], t + 1);
            }
            __syncthreads();
            #pragma unroll
            for (int a = 0; a < 4; ++a)
                #pragma unroll
                for (int h = 0; h < 2; ++h)
                    s[a][h] *= pre[a];
            const __hip_bfloat16* pb = phib + (size_t)(t & (RING - 1)) * BATCH * PHID;
            const __hip_bfloat16* pb0 = pb + (m0 + lrow) * PHID + 8 * quad;
            const __hip_bfloat16* pb1 = pb + (m0 + 16 + lrow) * PHID + 8 * quad;
            short8 fa[2][4][2];
            #pragma unroll
            for (int ki = 0; ki < 4; ++ki) {
                ldcc(fa[0][ki][0], pb0 + ki * 32);
                ldcc(fa[0][ki][1], pb1 + ki * 32);
            }
            #pragma unroll
            for (int g = 0; g < 4; ++g) {
                if (g < 3) {
                    #pragma unroll
                    for (int ki = 0; ki < 4; ++ki) {
                        ldcc(fa[(g + 1) & 1][ki][0], pb0 + (g + 1) * 128 + ki * 32);
                        ldcc(fa[(g + 1) & 1][ki][1], pb1 + (g + 1) * 128 + ki * 32);
                    }
                    WAITVM(8);
                } else {
                    WAITVM(0);
                }
                #pragma unroll
                for (int ki = 0; ki < 4; ++ki) {
                    const int k = g * 128 + ki * 32;
                    #pragma unroll
                    for (int a = 0; a < 4; ++a) {
                        const short8 b = *reinterpret_cast<const short8*>(
                            &wlds[(((a * 64 + (k >> 3) + quad) * 16 + lrow) << 3)]);
                        s[a][0] = MFMA(fa[g & 1][ki][0], b, s[a][0]);
                        s[a][1] = MFMA(fa[g & 1][ki][1], b, s[a][1]);
                    }
                }
            }
            #pragma unroll
            for (int a = 0; a < 4; ++a)
                #pragma unroll
                for (int h = 0; h < 2; ++h)
                    s[a][h] *= post[a];
        }
    } else {
        // ================= o-block =================
        const int ob = bid - 32, j0 = ob * 16;
        for (int i = tid * 4; i < 4 * 16 * 512; i += 1024) {
            const int a = i >> 13, rem = i & 8191;
            const int n = rem >> 9, k = rem & 511;
            const float4 v = *reinterpret_cast<const float4*>(
                &Wo[(j0 + n) * 2048 + a * 512 + k]);
            __hip_bfloat16* dst = &wlds[(((a * 64 + (k >> 3)) * 16 + n) << 3) + (k & 7)];
            dst[0] = __float2bfloat16(v.x); dst[1] = __float2bfloat16(v.y);
            dst[2] = __float2bfloat16(v.z); dst[3] = __float2bfloat16(v.w);
        }
        __syncthreads();
        const float pre[4]  = {0.f, 1.f, 9.f, 99.f};
        const float post[4] = {1.f, 0.5f, 0.1f, 0.01f};
        floatx4 o[4][2] = {};
        #pragma unroll 1
        for (int t = 0; t < SEQ; ++t) {
            if (tid < 16) {
                SPIN(&pfl[tid * 16], t + 1);
            }
            __syncthreads();
            #pragma unroll
            for (int a = 0; a < 4; ++a)
                #pragma unroll
                for (int h = 0; h < 2; ++h)
                    o[a][h] *= pre[a];
            const __hip_bfloat16* pb = phib + (size_t)(t & (RING - 1)) * BATCH * PHID;
            const __hip_bfloat16* pb0 = pb + (m0 + lrow) * PHID + 8 * quad;
            const __hip_bfloat16* pb1 = pb + (m0 + 16 + lrow) * PHID + 8 * quad;
            short8 fa[2][4][2];
            #pragma unroll
            for (int ki = 0; ki < 4; ++ki) {
                ldcc(fa[0][ki][0], pb0 + ki * 32);
                ldcc(fa[0][ki][1], pb1 + ki * 32);
            }
            #pragma unroll
            for (int g = 0; g < 4; ++g) {
                if (g < 3) {
                    #pragma unroll
                    for (int ki = 0; ki < 4; ++ki) {
                        ldcc(fa[(g + 1) & 1][ki][0], pb0 + (g + 1) * 128 + ki * 32);
                        ldcc(fa[(g + 1) & 1][ki][1], pb1 + (g + 1) * 128 + ki * 32);
                    }
                    WAITVM(8);
                } else {
                    WAITVM(0);
                }
                #pragma unroll
                for (int ki = 0; ki < 4; ++ki) {
                    const int k = g * 128 + ki * 32;
                    #pragma unroll
                    for (int a = 0; a < 4; ++a) {
                        const short8 b = *reinterpret_cast<const short8*>(
                            &wlds[(((a * 64 + (k >> 3) + quad) * 16 + lrow) << 3)]);
                        o[a][0] = MFMA(fa[g & 1][ki][0], b, o[a][0]);
                        o[a][1] = MFMA(fa[g & 1][ki][1], b, o[a][1]);
                    }
                }
            }
            #pragma unroll
            for (int a = 0; a < 4; ++a)
                #pragma unroll
                for (int h = 0; h < 2; ++h)
                    o[a][h] *= post[a];
            __syncthreads();                  // all waves' phi loads complete (WAITVM(0) above)
            if (tid == 0) flag_sc1(&ofl[ob * 16], t + 1);
        }
        const float bjo = bo[j0 + lrow];
        #pragma unroll
        for (int h = 0; h < 2; ++h)
            #pragma unroll
            for (int i = 0; i < 4; ++i) {
                const int row = m0 + 16 * h + quad * 4 + i;
                const float v = o[0][h][i] + o[1][h][i] + o[2][h][i] + o[3][h][i] + bjo;
                out[row * OUTD + j0 + lrow] = fmaxf(v, 0.f);
            }
    }
}

extern "C" void kernel_launch(void* const* d_in, const int* in_sizes, int n_in,
                              void* d_out, int out_size, void* d_ws, size_t ws_size,
                              hipStream_t stream)
{
    const float* x  = (const float*)d_in[0];
    const float* W1 = (const float*)d_in[1];
    const float* b1 = (const float*)d_in[2];
    const float* W2 = (const float*)d_in[3];
    const float* b2 = (const float*)d_in[4];
    const float* Wo = (const float*)d_in[5];
    const float* bo = (const float*)d_in[6];
    float* out = (float*)d_out;
    char* ws = (char*)d_ws;

    constexpr size_t O_CTRL = 0;                                  // 768 ints, 64B-spaced flags
    constexpr size_t O_RBF  = 4096;                               // 128x256 bf16 = 64 KB
    constexpr size_t O_PHI  = O_RBF + (size_t)BATCH * RD * 2;     // 16 x 128x512 bf16 = 2 MB
    constexpr size_t O_X    = O_PHI + (size_t)RING * BATCH * PHID * 2;  // 32 MB

    hipMemsetAsync(ws + O_CTRL, 0, 3072, stream);
    convert_x<<<SEQ * BATCH * XD / 4 / 256, 256, 0, stream>>>(
        x, (__hip_bfloat16*)(ws + O_X));
    sru_pipe<<<NBLK, 256, 0, stream>>>(
        W1, W2, Wo, b1, b2, bo,
        (const __hip_bfloat16*)(ws + O_X),
        (__hip_bfloat16*)(ws + O_RBF),
        (__hip_bfloat16*)(ws + O_PHI),
        out, (int*)(ws + O_CTRL));
}

// Round 6
// 4218.830 us; speedup vs baseline: 1.1742x; 1.1505x over previous
//
#include <hip/hip_runtime.h>
#include <hip/hip_bf16.h>

#define SEQ   512
#define BATCH 128
#define XD    256
#define PHID  512
#define RD    256
#define OUTD  256
#define NPHI  8
#define NS    16
#define NO    16
#define NBLK  (NPHI + NS + NO)
#define RING  16

typedef __attribute__((ext_vector_type(8))) short short8;
typedef __attribute__((ext_vector_type(4))) float floatx4;

#define MFMA(a, b, c) __builtin_amdgcn_mfma_f32_16x16x32_bf16((a), (b), (c), 0, 0, 0)

// counted vmem wait + scheduler pin (guide rule #18)
#define WAITVM(N) do { asm volatile("s_waitcnt vmcnt(" #N ")" ::: "memory"); \
                       __builtin_amdgcn_sched_barrier(0); } while (0)

__device__ inline short8 ldg8(const __hip_bfloat16* p) {
    return *reinterpret_cast<const short8*>(p);
}
// agent-coherent 16B load: sc1 bypasses (possibly stale) per-XCD L2, reads at LLC
__device__ inline void ldcc(short8& d, const __hip_bfloat16* p) {
    asm volatile("global_load_dwordx4 %0, %1, off sc1"
                 : "=v"(d) : "v"(p) : "memory");
}
// agent-coherent 2B store: write-through to LLC (never dirties L2)
__device__ inline void stcc16(__hip_bfloat16* p, __hip_bfloat16 v) {
    const short sv = __builtin_bit_cast(short, v);
    asm volatile("global_store_short %0, %1, off sc1"
                 :: "v"(p), "v"(sv) : "memory");
}
__device__ inline int flagld(const int* p) {
    return __hip_atomic_load(p, __ATOMIC_RELAXED, __HIP_MEMORY_SCOPE_AGENT);
}
// flag post: data stores already drained wave-locally (vmcnt(0)), plain sc1 store
__device__ inline void flag_sc1(int* p, int v) {
    asm volatile("global_store_dword %0, %1, off sc1"
                 :: "v"(p), "v"(v) : "memory");
}

__global__ void convert_x(const float* __restrict__ x, __hip_bfloat16* __restrict__ xbf) {
    const int gid = blockIdx.x * blockDim.x + threadIdx.x;   // grid covers N/4 exactly
    const float4 v = reinterpret_cast<const float4*>(x)[gid];
    __hip_bfloat16* d = xbf + 4 * (size_t)gid;
    d[0] = __float2bfloat16(v.x); d[1] = __float2bfloat16(v.y);
    d[2] = __float2bfloat16(v.z); d[3] = __float2bfloat16(v.w);
}

// 40 persistent blocks, WAVE-DECOUPLED: all flags are per (block, wave); the data
// flow is batch-row aligned (phi wave w produces rows 32w..32w+31; s/o wave w
// consumes exactly those rows), so the 4 waves form 4 independent pipelines.
// No __syncthreads in the t-loop. Roles:
//   bid  0..7  : phi-blocks — 64 cols of phi each (W2 slice = 64 KB LDS)
//   bid  8..23 : s-blocks   — 16 cols of r; s_a = mu_a @ W1_a^T in regs
//   bid 24..39 : o-blocks   — 16 cols of out; lag freely (ring 16)
// Protocol per wave: sc1 write-through stores -> s_waitcnt vmcnt(0) -> sc1 flag;
// consumer: ballot-spin on producer flags -> sc1 loads. (Twice-verified r2/r4.)
__global__ void __launch_bounds__(256) sru_pipe(
    const float* __restrict__ W1, const float* __restrict__ W2,
    const float* __restrict__ Wo,
    const float* __restrict__ b1, const float* __restrict__ b2,
    const float* __restrict__ bo,
    const __hip_bfloat16* __restrict__ xbf,
    __hip_bfloat16* __restrict__ rbf,
    __hip_bfloat16* __restrict__ phib,
    float* __restrict__ out, int* __restrict__ ctrl)
{
    __shared__ __hip_bfloat16 wlds[32768];   // 64 KB
    const int bid  = blockIdx.x;
    const int tid  = threadIdx.x;
    const int wave = tid >> 6;
    const int lane = tid & 63;
    const int quad = lane >> 4;
    const int lrow = lane & 15;
    const int m0   = wave * 32;              // each wave owns 32 batch rows
    int* rfl = ctrl;                         // (sb*4+w)*16   : 1024 ints
    int* pfl = ctrl + 1024;                  // (p*4+w)*16    : 512 ints
    int* ofl = ctrl + 1536;                  // (ob*4+w)*16   : 1024 ints

    if (bid < NPHI) {
        // ================= phi-block (64 cols) =================
        const int j0 = bid * 64;
        for (int i = tid * 4; i < 64 * 512; i += 1024) {
            const int n = i >> 9, k = i & 511;
            const int part = k >> 8, kk = k & 255;
            const float4 v = *reinterpret_cast<const float4*>(&W2[(j0 + n) * 512 + k]);
            __hip_bfloat16* dst = &wlds[(((part * 32 + (kk >> 3)) * 64 + n) << 3) + (kk & 7)];
            dst[0] = __float2bfloat16(v.x); dst[1] = __float2bfloat16(v.y);
            dst[2] = __float2bfloat16(v.z); dst[3] = __float2bfloat16(v.w);
        }
        __syncthreads();                     // only barrier: weights resident
        float bj[4];
        #pragma unroll
        for (int j2 = 0; j2 < 4; ++j2) bj[j2] = b2[j0 + j2 * 16 + lrow];
        const __hip_bfloat16* rb0 = rbf + (m0 + lrow) * RD + 8 * quad;
        const __hip_bfloat16* rb1 = rbf + (m0 + 16 + lrow) * RD + 8 * quad;
        #pragma unroll 1
        for (int t = 0; t < SEQ; ++t) {
            floatx4 acc[2][4] = {};
            // x-part (no dependency on this step's r) — overlaps the r-wait below
            const __hip_bfloat16* xt = xbf + (size_t)(t * BATCH + m0) * XD;
            #pragma unroll
            for (int k = 0; k < XD; k += 32) {
                const short8 a0 = ldg8(xt + lrow * XD + k + 8 * quad);
                const short8 a1 = ldg8(xt + (16 + lrow) * XD + k + 8 * quad);
                #pragma unroll
                for (int j2 = 0; j2 < 4; ++j2) {
                    const short8 b = *reinterpret_cast<const short8*>(
                        &wlds[((((k >> 3) + quad) * 64 + j2 * 16 + lrow) << 3)]);
                    acc[0][j2] = MFMA(a0, b, acc[0][j2]);
                    acc[1][j2] = MFMA(a1, b, acc[1][j2]);
                }
            }
            // per-wave wait: r_t rows m0.. from 16 s-waves; o-gate on ring slot
            {
                int guard = 0;
                while (true) {
                    bool nr = false;
                    if (lane < 16)      nr = flagld(&rfl[(lane * 4 + wave) * 16]) < t + 1;
                    else if (lane < 32) nr = flagld(&ofl[((lane - 16) * 4 + wave) * 16]) < t - (RING - 1);
                    if (__ballot(nr) == 0) break;
                    if (++guard > 16384) break;     // hang-proofing
                }
            }
            // r-part: LLC loads, double-buffered counted-vmcnt batches
            short8 ra[2][4][2];
            #pragma unroll
            for (int ki = 0; ki < 4; ++ki) {
                ldcc(ra[0][ki][0], rb0 + ki * 32);
                ldcc(ra[0][ki][1], rb1 + ki * 32);
            }
            #pragma unroll
            for (int g = 0; g < 2; ++g) {
                if (g == 0) {
                    #pragma unroll
                    for (int ki = 0; ki < 4; ++ki) {
                        ldcc(ra[1][ki][0], rb0 + 128 + ki * 32);
                        ldcc(ra[1][ki][1], rb1 + 128 + ki * 32);
                    }
                    WAITVM(8);
                } else {
                    WAITVM(0);
                }
                #pragma unroll
                for (int ki = 0; ki < 4; ++ki) {
                    const int k = g * 128 + ki * 32;
                    #pragma unroll
                    for (int j2 = 0; j2 < 4; ++j2) {
                        const short8 b = *reinterpret_cast<const short8*>(
                            &wlds[(((32 + (k >> 3) + quad) * 64 + j2 * 16 + lrow) << 3)]);
                        acc[0][j2] = MFMA(ra[g][ki][0], b, acc[0][j2]);
                        acc[1][j2] = MFMA(ra[g][ki][1], b, acc[1][j2]);
                    }
                }
            }
            __hip_bfloat16* pb = phib + (size_t)(t & (RING - 1)) * BATCH * PHID;
            #pragma unroll
            for (int h = 0; h < 2; ++h)
                #pragma unroll
                for (int j2 = 0; j2 < 4; ++j2)
                    #pragma unroll
                    for (int i = 0; i < 4; ++i) {
                        const int row = m0 + 16 * h + quad * 4 + i;
                        const float v = acc[h][j2][i] + bj[j2];
                        stcc16(pb + row * PHID + j0 + j2 * 16 + lrow,
                               __float2bfloat16(fmaxf(v, 0.f)));
                    }
            asm volatile("s_waitcnt vmcnt(0)" ::: "memory");   // wave's stores at LLC
            if (lane == 0) flag_sc1(&pfl[(bid * 4 + wave) * 16], t + 1);
        }
    } else if (bid < NPHI + NS) {
        // ================= s-block =================
        const int sb = bid - NPHI, j0 = sb * 16;
        for (int i = tid * 4; i < 4 * 16 * 512; i += 1024) {
            const int a = i >> 13, rem = i & 8191;
            const int n = rem >> 9, k = rem & 511;
            const float4 v = *reinterpret_cast<const float4*>(
                &W1[(j0 + n) * 2048 + a * 512 + k]);
            __hip_bfloat16* dst = &wlds[(((a * 64 + (k >> 3)) * 16 + n) << 3) + (k & 7)];
            dst[0] = __float2bfloat16(v.x); dst[1] = __float2bfloat16(v.y);
            dst[2] = __float2bfloat16(v.z); dst[3] = __float2bfloat16(v.w);
        }
        __syncthreads();
        const float bjv = b1[j0 + lrow];
        const float pre[4]  = {0.f, 1.f, 9.f, 99.f};    // alpha/(1-alpha)
        const float post[4] = {1.f, 0.5f, 0.1f, 0.01f}; // (1-alpha)
        floatx4 s[4][2] = {};
        #pragma unroll 1
        for (int t = 0; t < SEQ; ++t) {
            // emit r_t rows m0.. (write-through), wave-local drain, per-wave flag
            #pragma unroll
            for (int h = 0; h < 2; ++h)
                #pragma unroll
                for (int i = 0; i < 4; ++i) {
                    const int row = m0 + 16 * h + quad * 4 + i;
                    const float rv = s[0][h][i] + s[1][h][i] + s[2][h][i] + s[3][h][i] + bjv;
                    stcc16(rbf + row * RD + j0 + lrow, __float2bfloat16(fmaxf(rv, 0.f)));
                }
            asm volatile("s_waitcnt vmcnt(0)" ::: "memory");
            if (lane == 0) flag_sc1(&rfl[(sb * 4 + wave) * 16], t + 1);
            if (t == SEQ - 1) break;
            // wait phi_t rows m0.. from the 8 phi-waves
            {
                int guard = 0;
                while (true) {
                    bool nr = false;
                    if (lane < 8) nr = flagld(&pfl[(lane * 4 + wave) * 16]) < t + 1;
                    if (__ballot(nr) == 0) break;
                    if (++guard > 16384) break;
                }
            }
            #pragma unroll
            for (int a = 0; a < 4; ++a)
                #pragma unroll
                for (int h = 0; h < 2; ++h)
                    s[a][h] *= pre[a];
            const __hip_bfloat16* pb = phib + (size_t)(t & (RING - 1)) * BATCH * PHID;
            const __hip_bfloat16* pb0 = pb + (m0 + lrow) * PHID + 8 * quad;
            const __hip_bfloat16* pb1 = pb + (m0 + 16 + lrow) * PHID + 8 * quad;
            short8 fa[2][4][2];
            #pragma unroll
            for (int ki = 0; ki < 4; ++ki) {
                ldcc(fa[0][ki][0], pb0 + ki * 32);
                ldcc(fa[0][ki][1], pb1 + ki * 32);
            }
            #pragma unroll
            for (int g = 0; g < 4; ++g) {
                if (g < 3) {
                    #pragma unroll
                    for (int ki = 0; ki < 4; ++ki) {
                        ldcc(fa[(g + 1) & 1][ki][0], pb0 + (g + 1) * 128 + ki * 32);
                        ldcc(fa[(g + 1) & 1][ki][1], pb1 + (g + 1) * 128 + ki * 32);
                    }
                    WAITVM(8);
                } else {
                    WAITVM(0);
                }
                #pragma unroll
                for (int ki = 0; ki < 4; ++ki) {
                    const int k = g * 128 + ki * 32;
                    #pragma unroll
                    for (int a = 0; a < 4; ++a) {
                        const short8 b = *reinterpret_cast<const short8*>(
                            &wlds[(((a * 64 + (k >> 3) + quad) * 16 + lrow) << 3)]);
                        s[a][0] = MFMA(fa[g & 1][ki][0], b, s[a][0]);
                        s[a][1] = MFMA(fa[g & 1][ki][1], b, s[a][1]);
                    }
                }
            }
            #pragma unroll
            for (int a = 0; a < 4; ++a)
                #pragma unroll
                for (int h = 0; h < 2; ++h)
                    s[a][h] *= post[a];
        }
    } else {
        // ================= o-block =================
        const int ob = bid - NPHI - NS, j0 = ob * 16;
        for (int i = tid * 4; i < 4 * 16 * 512; i += 1024) {
            const int a = i >> 13, rem = i & 8191;
            const int n = rem >> 9, k = rem & 511;
            const float4 v = *reinterpret_cast<const float4*>(
                &Wo[(j0 + n) * 2048 + a * 512 + k]);
            __hip_bfloat16* dst = &wlds[(((a * 64 + (k >> 3)) * 16 + n) << 3) + (k & 7)];
            dst[0] = __float2bfloat16(v.x); dst[1] = __float2bfloat16(v.y);
            dst[2] = __float2bfloat16(v.z); dst[3] = __float2bfloat16(v.w);
        }
        __syncthreads();
        const float pre[4]  = {0.f, 1.f, 9.f, 99.f};
        const float post[4] = {1.f, 0.5f, 0.1f, 0.01f};
        floatx4 o[4][2] = {};
        #pragma unroll 1
        for (int t = 0; t < SEQ; ++t) {
            {
                int guard = 0;
                while (true) {
                    bool nr = false;
                    if (lane < 8) nr = flagld(&pfl[(lane * 4 + wave) * 16]) < t + 1;
                    if (__ballot(nr) == 0) break;
                    if (++guard > 16384) break;
                }
            }
            #pragma unroll
            for (int a = 0; a < 4; ++a)
                #pragma unroll
                for (int h = 0; h < 2; ++h)
                    o[a][h] *= pre[a];
            const __hip_bfloat16* pb = phib + (size_t)(t & (RING - 1)) * BATCH * PHID;
            const __hip_bfloat16* pb0 = pb + (m0 + lrow) * PHID + 8 * quad;
            const __hip_bfloat16* pb1 = pb + (m0 + 16 + lrow) * PHID + 8 * quad;
            short8 fa[2][4][2];
            #pragma unroll
            for (int ki = 0; ki < 4; ++ki) {
                ldcc(fa[0][ki][0], pb0 + ki * 32);
                ldcc(fa[0][ki][1], pb1 + ki * 32);
            }
            #pragma unroll
            for (int g = 0; g < 4; ++g) {
                if (g < 3) {
                    #pragma unroll
                    for (int ki = 0; ki < 4; ++ki) {
                        ldcc(fa[(g + 1) & 1][ki][0], pb0 + (g + 1) * 128 + ki * 32);
                        ldcc(fa[(g + 1) & 1][ki][1], pb1 + (g + 1) * 128 + ki * 32);
                    }
                    WAITVM(8);
                } else {
                    WAITVM(0);
                }
                #pragma unroll
                for (int ki = 0; ki < 4; ++ki) {
                    const int k = g * 128 + ki * 32;
                    #pragma unroll
                    for (int a = 0; a < 4; ++a) {
                        const short8 b = *reinterpret_cast<const short8*>(
                            &wlds[(((a * 64 + (k >> 3) + quad) * 16 + lrow) << 3)]);
                        o[a][0] = MFMA(fa[g & 1][ki][0], b, o[a][0]);
                        o[a][1] = MFMA(fa[g & 1][ki][1], b, o[a][1]);
                    }
                }
            }
            #pragma unroll
            for (int a = 0; a < 4; ++a)
                #pragma unroll
                for (int h = 0; h < 2; ++h)
                    o[a][h] *= post[a];
            // WAITVM(0) above: this wave's phi loads complete -> safe to release slot
            if (lane == 0) flag_sc1(&ofl[(ob * 4 + wave) * 16], t + 1);
        }
        const float bjo = bo[j0 + lrow];
        #pragma unroll
        for (int h = 0; h < 2; ++h)
            #pragma unroll
            for (int i = 0; i < 4; ++i) {
                const int row = m0 + 16 * h + quad * 4 + i;
                const float v = o[0][h][i] + o[1][h][i] + o[2][h][i] + o[3][h][i] + bjo;
                out[row * OUTD + j0 + lrow] = fmaxf(v, 0.f);
            }
    }
}

extern "C" void kernel_launch(void* const* d_in, const int* in_sizes, int n_in,
                              void* d_out, int out_size, void* d_ws, size_t ws_size,
                              hipStream_t stream)
{
    const float* x  = (const float*)d_in[0];
    const float* W1 = (const float*)d_in[1];
    const float* b1 = (const float*)d_in[2];
    const float* W2 = (const float*)d_in[3];
    const float* b2 = (const float*)d_in[4];
    const float* Wo = (const float*)d_in[5];
    const float* bo = (const float*)d_in[6];
    float* out = (float*)d_out;
    char* ws = (char*)d_ws;

    constexpr size_t O_CTRL = 0;                                  // 2560 ints (per-wave flags)
    constexpr size_t O_RBF  = 16384;                              // 128x256 bf16 = 64 KB
    constexpr size_t O_PHI  = O_RBF + (size_t)BATCH * RD * 2;     // 16 x 128x512 bf16 = 2 MB
    constexpr size_t O_X    = O_PHI + (size_t)RING * BATCH * PHID * 2;  // 32 MB

    hipMemsetAsync(ws + O_CTRL, 0, 12288, stream);
    convert_x<<<SEQ * BATCH * XD / 4 / 256, 256, 0, stream>>>(
        x, (__hip_bfloat16*)(ws + O_X));
    sru_pipe<<<NBLK, 256, 0, stream>>>(
        W1, W2, Wo, b1, b2, bo,
        (const __hip_bfloat16*)(ws + O_X),
        (__hip_bfloat16*)(ws + O_RBF),
        (__hip_bfloat16*)(ws + O_PHI),
        out, (int*)(ws + O_CTRL));
}